// Round 4
// baseline (78.943 us; speedup 1.0000x reference)
//
#include <hip/hip_runtime.h>

// SparseLookupTable: out[b,o] = sum_{k<128} lut[inp[b,k], wgt[o,k]]
// B=512, O=1024, K=128, LUT 256x256 fp32.
//
// R4: LDS-pipe is the bottleneck (~16 cyc per random wave64 gather). Offload:
//  - rows r<64 (25% of gathers) gathered from a 32 KB fp16 sub-table in d_ws
//    (L1-resident) via the VMEM pipe, scalar-branched (row is wave-uniform).
//  - row indices via s_load (scalar cache) -- uniform pointer.
//  - columns stay LDS-staged (16 waves reuse them); gathers r>=64 from LDS LUT.

#define OUTF  1024
#define KDIM  128
#define MIDX  256

typedef _Float16 half4v __attribute__((ext_vector_type(4)));

__global__ __launch_bounds__(1024, 1)
void slt_kernel(const int* __restrict__ inp, const int* __restrict__ wgt,
                const float* __restrict__ lut, float* __restrict__ out,
                _Float16* __restrict__ wst) {
    // 128 KB LUT + 16 KB packed cols = 144 KB LDS
    __shared__ __attribute__((aligned(16))) _Float16 lut16[MIDX * MIDX];
    __shared__ __attribute__((aligned(16))) unsigned int wcol_pack[8 * 128 * 4]; // [g][o][j]

    const int tid   = threadIdx.x;
    const int otile = blockIdx.x;   // 8 tiles of 128 outputs
    const int btile = blockIdx.y;   // 32 tiles of 16 batch rows

    // ---- stage LUT fp32 -> fp16 into LDS; rows 0..63 also to ws sub-table ----
    const float4* lut4 = (const float4*)lut;
    half4v* l16v = (half4v*)lut16;
    half4v* wsv  = (half4v*)wst;
    #pragma unroll
    for (int it = 0; it < 16; ++it) {
        int idx = it * 1024 + tid;
        float4 v = lut4[idx];
        half4v h = { (_Float16)v.x, (_Float16)v.y, (_Float16)v.z, (_Float16)v.w };
        l16v[idx] = h;
        if (it < 4) wsv[idx] = h;   // rows 0..63 (32 KB), identical across blocks
    }

    // ---- stage packed col indices: wcol_pack[(q>>2)*512 + o*4 + (q&3)] ----
    {
        int o  = tid >> 3;          // 0..127
        int jj = tid & 7;
        const int* wbase = wgt + ((size_t)(otile * 128 + o)) * KDIM;
        #pragma unroll
        for (int i = 0; i < 4; ++i) {
            int q = jj + 8 * i;     // coalesced int4 reads
            const int4 wv = *(const int4*)(wbase + q * 4);
            unsigned int pw = (unsigned int)(wv.x & 255)
                            | ((unsigned int)(wv.y & 255) << 8)
                            | ((unsigned int)(wv.z & 255) << 16)
                            | ((unsigned int)(wv.w & 255) << 24);
            wcol_pack[(q >> 2) * 512 + o * 4 + (q & 3)] = pw;
        }
    }

    __syncthreads();   // also drains vmem: ws sub-table visible to this block

    const int w    = __builtin_amdgcn_readfirstlane(tid >> 6); // wave id = b-row (SGPR)
    const int lane = tid & 63;                                  // o = lane, lane+64
    const int* rowp = inp + ((size_t)(btile * 16 + w)) * KDIM;  // uniform -> s_load

    float a0 = 0.f, a1 = 0.f, b0 = 0.f, b1 = 0.f;  // LDS-path accumulators
    float v0 = 0.f, v1 = 0.f;                      // VMEM-path accumulators

    #pragma unroll 2
    for (int g = 0; g < 8; ++g) {
        uint4 cw0 = *(const uint4*)&wcol_pack[g * 512 + lane * 4];
        uint4 cw1 = *(const uint4*)&wcol_pack[g * 512 + (lane + 64) * 4];
        unsigned int w0s[4] = { cw0.x, cw0.y, cw0.z, cw0.w };
        unsigned int w1s[4] = { cw1.x, cw1.y, cw1.z, cw1.w };

        #pragma unroll
        for (int j = 0; j < 4; ++j) {
            unsigned int u0 = w0s[j], u1 = w1s[j];
            #pragma unroll
            for (int m = 0; m < 4; ++m) {
                int r   = rowp[g * 16 + j * 4 + m];            // s_load, SGPR
                int cc0 = (int)((u0 >> (8 * m)) & 255u);
                int cc1 = (int)((u1 >> (8 * m)) & 255u);
                if (r < 64) {                                  // scalar branch
                    const _Float16* p = wst + (r << 8);        // L1-resident
                    v0 += (float)p[cc0];
                    v1 += (float)p[cc1];
                } else {
                    const _Float16* p = lut16 + (r << 8);      // LDS
                    if (m & 1) { b0 += (float)p[cc0]; b1 += (float)p[cc1]; }
                    else       { a0 += (float)p[cc0]; a1 += (float)p[cc1]; }
                }
            }
        }
    }

    size_t ob = ((size_t)(btile * 16 + w)) * OUTF + (size_t)(otile * 128) + lane;
    out[ob]      = a0 + b0 + v0;
    out[ob + 64] = a1 + b1 + v1;
}

extern "C" void kernel_launch(void* const* d_in, const int* in_sizes, int n_in,
                              void* d_out, int out_size, void* d_ws, size_t ws_size,
                              hipStream_t stream) {
    const int*   inp = (const int*)d_in[0];    // (512, 32, 4) int32
    const int*   wgt = (const int*)d_in[1];    // (1024, 32, 4) int32
    const float* lut = (const float*)d_in[2];  // (256, 256) fp32
    float*       out = (float*)d_out;          // (512, 1024) fp32
    _Float16*    wst = (_Float16*)d_ws;        // 32 KB fp16 sub-table (rows 0..63)

    dim3 grid(8, 32);   // 256 blocks, ~1 per CU
    dim3 block(1024);
    slt_kernel<<<grid, block, 0, stream>>>(inp, wgt, lut, out, wst);
}

// Round 6
// 74.408 us; speedup vs baseline: 1.0610x; 1.0610x over previous
//
#include <hip/hip_runtime.h>

// SparseLookupTable: out[b,o] = sum_{k<128} lut[inp[b,k], wgt[o,k]]
// B=512, O=1024, K=128, LUT 256x256 fp32.
//
// R6 = R3 frame (verified stable: LDS-staged indices, coalesced global reads,
// wave-uniform rows -> SALU bases) + pair-packed fp16 LUT so every gather is a
// full-word ds_read_b32 (tests the ds_read_u16 sub-word-penalty theory).

#define OUTF  1024
#define KDIM  128
#define MIDX  256

__global__ __launch_bounds__(1024, 1)
void slt_kernel(const int* __restrict__ inp, const int* __restrict__ wgt,
                const float* __restrict__ lut, float* __restrict__ out) {
    // 128 KB pair-packed LUT + 2 KB rows + 16 KB cols = 146 KB LDS
    __shared__ __attribute__((aligned(16))) unsigned int lutw[MIDX * (MIDX / 2)]; // [r][c>>1]
    __shared__ __attribute__((aligned(16))) unsigned int wrow_pack[16 * 32];      // [b][q]
    __shared__ __attribute__((aligned(16))) unsigned int wcol_pack[8 * 128 * 4];  // [g][o][j]

    const int tid   = threadIdx.x;
    const int otile = blockIdx.x;   // 8 tiles of 128 outputs
    const int btile = blockIdx.y;   // 32 tiles of 16 batch rows

    // ---- stage LUT fp32 -> fp16-pair words, b128 LDS writes ----
    {
        const float4* lut4 = (const float4*)lut;
        uint4* dst = (uint4*)lutw;
        #pragma unroll
        for (int it = 0; it < 8; ++it) {
            int idx = it * 1024 + tid;
            float4 v0 = lut4[2 * idx];
            float4 v1 = lut4[2 * idx + 1];
            union { _Float16 h[8]; uint4 u; } pk;
            pk.h[0] = (_Float16)v0.x; pk.h[1] = (_Float16)v0.y;
            pk.h[2] = (_Float16)v0.z; pk.h[3] = (_Float16)v0.w;
            pk.h[4] = (_Float16)v1.x; pk.h[5] = (_Float16)v1.y;
            pk.h[6] = (_Float16)v1.z; pk.h[7] = (_Float16)v1.w;
            dst[idx] = pk.u;
        }
    }

    // ---- stage input rows, u8-packed: wrow_pack[b*32+q] = inp[b][4q..4q+3] ----
    if (tid < 512) {
        int b = tid >> 5;
        int q = tid & 31;
        const int4 iv = *(const int4*)(inp + ((size_t)(btile * 16 + b)) * KDIM + q * 4);
        wrow_pack[b * 32 + q] = (unsigned int)(iv.x & 255)
                              | ((unsigned int)(iv.y & 255) << 8)
                              | ((unsigned int)(iv.z & 255) << 16)
                              | ((unsigned int)(iv.w & 255) << 24);
    }

    // ---- stage weight cols, u8-packed, blocked: wcol_pack[(q>>2)*512 + o*4 + (q&3)] ----
    {
        int o  = tid >> 3;          // 0..127
        int jj = tid & 7;
        const int* wbase = wgt + ((size_t)(otile * 128 + o)) * KDIM;
        #pragma unroll
        for (int i = 0; i < 4; ++i) {
            int q = jj + 8 * i;     // coalesced int4 reads
            const int4 wv = *(const int4*)(wbase + q * 4);
            unsigned int pw = (unsigned int)(wv.x & 255)
                            | ((unsigned int)(wv.y & 255) << 8)
                            | ((unsigned int)(wv.z & 255) << 16)
                            | ((unsigned int)(wv.w & 255) << 24);
            wcol_pack[(q >> 2) * 512 + o * 4 + (q & 3)] = pw;
        }
    }

    __syncthreads();

    const int w    = tid >> 6;  // wave id = b-row within tile
    const int lane = tid & 63;  // o = lane and lane+64

    float a0 = 0.f, a1 = 0.f, b0 = 0.f, b1 = 0.f;

    #pragma unroll 2
    for (int g = 0; g < 8; ++g) {
        // one broadcast b128: rows for 16 k's (wave-uniform)
        uint4 rw = *(const uint4*)&wrow_pack[w * 32 + 4 * g];
        // two b128s: packed cols for 16 k's, o=lane and o=lane+64
        uint4 c0v = *(const uint4*)&wcol_pack[g * 512 + lane * 4];
        uint4 c1v = *(const uint4*)&wcol_pack[g * 512 + (lane + 64) * 4];

        unsigned int rws[4] = { rw.x, rw.y, rw.z, rw.w };
        unsigned int w0s[4] = { c0v.x, c0v.y, c0v.z, c0v.w };
        unsigned int w1s[4] = { c1v.x, c1v.y, c1v.z, c1v.w };

        #pragma unroll
        for (int j = 0; j < 4; ++j) {
            unsigned int rword = (unsigned int)__builtin_amdgcn_readfirstlane((int)rws[j]);
            // scalar row bases (word index into lutw; row stride = 128 words)
            const unsigned int* rb0 = lutw + ((rword       & 255u) << 7);
            const unsigned int* rb1 = lutw + (((rword >>  8) & 255u) << 7);
            const unsigned int* rb2 = lutw + (((rword >> 16) & 255u) << 7);
            const unsigned int* rb3 = lutw + ((rword >> 24) << 7);
            unsigned int u0 = w0s[j], u1 = w1s[j];

            unsigned int c00 = u0 & 255u,         c01 = u1 & 255u;
            unsigned int c10 = (u0 >>  8) & 255u, c11 = (u1 >>  8) & 255u;
            unsigned int c20 = (u0 >> 16) & 255u, c21 = (u1 >> 16) & 255u;
            unsigned int c30 = u0 >> 24,          c31 = u1 >> 24;

            unsigned int h00 = rb0[c00 >> 1] >> ((c00 & 1u) << 4);
            unsigned int h01 = rb0[c01 >> 1] >> ((c01 & 1u) << 4);
            unsigned int h10 = rb1[c10 >> 1] >> ((c10 & 1u) << 4);
            unsigned int h11 = rb1[c11 >> 1] >> ((c11 & 1u) << 4);
            unsigned int h20 = rb2[c20 >> 1] >> ((c20 & 1u) << 4);
            unsigned int h21 = rb2[c21 >> 1] >> ((c21 & 1u) << 4);
            unsigned int h30 = rb3[c30 >> 1] >> ((c30 & 1u) << 4);
            unsigned int h31 = rb3[c31 >> 1] >> ((c31 & 1u) << 4);

            a0 += (float)*(_Float16*)&h00;  a1 += (float)*(_Float16*)&h01;
            b0 += (float)*(_Float16*)&h10;  b1 += (float)*(_Float16*)&h11;
            a0 += (float)*(_Float16*)&h20;  a1 += (float)*(_Float16*)&h21;
            b0 += (float)*(_Float16*)&h30;  b1 += (float)*(_Float16*)&h31;
        }
    }

    size_t ob = ((size_t)(btile * 16 + w)) * OUTF + (size_t)(otile * 128) + lane;
    out[ob]      = a0 + b0;
    out[ob + 64] = a1 + b1;
}

extern "C" void kernel_launch(void* const* d_in, const int* in_sizes, int n_in,
                              void* d_out, int out_size, void* d_ws, size_t ws_size,
                              hipStream_t stream) {
    const int*   inp = (const int*)d_in[0];    // (512, 32, 4) int32
    const int*   wgt = (const int*)d_in[1];    // (1024, 32, 4) int32
    const float* lut = (const float*)d_in[2];  // (256, 256) fp32
    float*       out = (float*)d_out;          // (512, 1024) fp32

    dim3 grid(8, 32);   // 256 blocks, ~1 per CU
    dim3 block(1024);
    slt_kernel<<<grid, block, 0, stream>>>(inp, wgt, lut, out);
}